// Round 11
// baseline (218.556 us; speedup 1.0000x reference)
//
#include <hip/hip_runtime.h>
#include <hip/hip_bf16.h>
#include <math.h>

// Problem constants
// x:(4,128,96,96) gate_w:(8,128,3,3) gate_bias:(8) expert_w:(8,128,128,3,3)
// expert_b:(8,128) shared_w:(128,128,3,3) shared_b:(128)  -> out:(4,128,96,96)

typedef __attribute__((ext_vector_type(8))) short short8;
typedef __attribute__((ext_vector_type(4))) float f32x4;

static __device__ __forceinline__ unsigned short f2bf(float f) {
    unsigned int u = __float_as_uint(f);
    unsigned int r = (u + 0x7FFFu + ((u >> 16) & 1u)) >> 16;
    return (unsigned short)r;
}

// ---------------------------------------------------------------------------
// Merged gate + prep kernel.
//   blocks [0,576):  gate — fp32 conv -> sigmoid -> top2 -> softmax -> scores.
//                    Weights loaded via explicit s_load inline asm: the 64-bit
//                    address is built from readfirstlane'd halves (SGPR-class,
//                    so the "s" constraint is satisfiable — fixes R4's
//                    invalid-operand failure). 24 s_loads/ci -> 72 SGPRs;
//                    inner loop = v_fmac with SGPR weight operands.
//                    Per-accumulator FP order == R1 gate (bitwise-same).
//   blocks [576,720): prep — coalesced transpose of expert_w + shared_w into
//                    bf16 pw in MFMA-fragment order via an LDS bounce
//                    (verified bit-identical layout, R5/R7/R10 passes).
// ---------------------------------------------------------------------------
__global__ __launch_bounds__(256) void gate_prep_kernel(
    const float* __restrict__ x, const float* __restrict__ gw,
    const float* __restrict__ gb,
    const float* __restrict__ ew, const float* __restrict__ sw,
    float* __restrict__ scores, unsigned short* __restrict__ pw)
{
    __shared__ float red[4][64][8];            // gate partial sums (8 KB)
    __shared__ unsigned short lt2[9216];       // prep bounce (18 KB)

    const int t  = threadIdx.x;
    const int bx = blockIdx.x;

    if (bx >= 576) {
        // =================== prep transpose (144 blocks) ====================
        // pw chunk index: (e*9+tap)*2048 + wv*512 + kc*128 + h*64 + lane
        //   lane = lq*16+lm ; co = wv*32+h*16+lm ; k = kc*32+lq*8+d
        const int pblk = bx - 576;
        const int e  = pblk >> 4;
        const int wv = (pblk >> 2) & 3;
        const int kc = pblk & 3;
        const float* src = (e < 8) ? (ew + e * 147456) : sw;
        const float* sb2 = src + (wv * 32) * 1152 + kc * 288;

        #pragma unroll
        for (int j = 0; j < 36; ++j) {
            int i = t + j * 256;                 // 0..9215
            int co_l = i / 288;
            int r    = i - co_l * 288;           // k_l*9 + tap
            int k_l  = r / 9;
            int tap  = r - k_l * 9;
            float v = sb2[co_l * 1152 + r];
            lt2[tap * 1024 + (co_l >> 4) * 512 +
                ((k_l >> 3) * 16 + (co_l & 15)) * 8 + (k_l & 7)] = f2bf(v);
        }
        __syncthreads();

        uint4* pw16 = reinterpret_cast<uint4*>(pw);
        for (int c = t; c < 1152; c += 256) {
            int tap = c >> 7;
            int rem = c & 127;                   // h*64 + lane
            uint4 val = *reinterpret_cast<const uint4*>(&lt2[tap * 1024 + rem * 8]);
            pw16[(e * 9 + tap) * 2048 + wv * 512 + kc * 128 + rem] = val;
        }
        return;
    }

    // ======================= gate (576 blocks) ==============================
    const int g  = t >> 6;               // ci group (wave id)
    const int p  = t & 63;
    const int wt = bx % 3;
    const int h2 = (bx / 3) % 48;
    const int b  = bx / 144;
    const int h  = h2 * 2 + (p >> 5);
    const int w  = wt * 32 + (p & 31);

    int off[9]; float msk[9];
    #pragma unroll
    for (int kh = 0; kh < 3; kh++) {
        #pragma unroll
        for (int kw = 0; kw < 3; kw++) {
            int hh = h + kh - 1, ww = w + kw - 1;
            bool valid = (hh >= 0 && hh < 96 && ww >= 0 && ww < 96);
            int hc = min(max(hh, 0), 95), wc = min(max(ww, 0), 95);
            off[kh * 3 + kw] = hc * 96 + wc;
            msk[kh * 3 + kw] = valid ? 1.0f : 0.0f;
        }
    }

    // wave-uniform bases; address halves forced into SGPR class
    const int gu = __builtin_amdgcn_readfirstlane(g);
    const float* xb = x + (b * 128 + gu * 32) * 9216;
    const unsigned long long a64 =
        (unsigned long long)(uintptr_t)(gw + gu * 288);   // += gu*1152 bytes
    const unsigned int alo = __builtin_amdgcn_readfirstlane((unsigned int)a64);
    const unsigned int ahi = __builtin_amdgcn_readfirstlane((unsigned int)(a64 >> 32));

    float acc[8] = {0.f,0.f,0.f,0.f,0.f,0.f,0.f,0.f};
    #pragma unroll 1
    for (int ci = 0; ci < 32; ci++) {
        const float* xc = xb + ci * 9216;
        float xv[9];
        #pragma unroll
        for (int tap = 0; tap < 9; tap++) xv[tap] = xc[off[tap]] * msk[tap];

        // w[ci][e*9+tap] = gw[(e*128 + gu*32+ci)*9 + tap]
        //   = *(byte*)(a64 + ci*36 + e*4608 + tap*4)
        const unsigned long long sa =
            ((((unsigned long long)ahi) << 32) | alo) + (unsigned long long)(ci * 36);
        f32x4 wA[8], wB[8]; float wC[8];
        asm volatile(
            "s_load_dwordx4 %0,  %24, 0x0\n\t"
            "s_load_dwordx4 %8,  %24, 0x10\n\t"
            "s_load_dword   %16, %24, 0x20\n\t"
            "s_load_dwordx4 %1,  %24, 0x1200\n\t"
            "s_load_dwordx4 %9,  %24, 0x1210\n\t"
            "s_load_dword   %17, %24, 0x1220\n\t"
            "s_load_dwordx4 %2,  %24, 0x2400\n\t"
            "s_load_dwordx4 %10, %24, 0x2410\n\t"
            "s_load_dword   %18, %24, 0x2420\n\t"
            "s_load_dwordx4 %3,  %24, 0x3600\n\t"
            "s_load_dwordx4 %11, %24, 0x3610\n\t"
            "s_load_dword   %19, %24, 0x3620\n\t"
            "s_load_dwordx4 %4,  %24, 0x4800\n\t"
            "s_load_dwordx4 %12, %24, 0x4810\n\t"
            "s_load_dword   %20, %24, 0x4820\n\t"
            "s_load_dwordx4 %5,  %24, 0x5a00\n\t"
            "s_load_dwordx4 %13, %24, 0x5a10\n\t"
            "s_load_dword   %21, %24, 0x5a20\n\t"
            "s_load_dwordx4 %6,  %24, 0x6c00\n\t"
            "s_load_dwordx4 %14, %24, 0x6c10\n\t"
            "s_load_dword   %22, %24, 0x6c20\n\t"
            "s_load_dwordx4 %7,  %24, 0x7e00\n\t"
            "s_load_dwordx4 %15, %24, 0x7e10\n\t"
            "s_load_dword   %23, %24, 0x7e20\n\t"
            "s_waitcnt lgkmcnt(0)"
            : "=s"(wA[0]), "=s"(wA[1]), "=s"(wA[2]), "=s"(wA[3]),
              "=s"(wA[4]), "=s"(wA[5]), "=s"(wA[6]), "=s"(wA[7]),
              "=s"(wB[0]), "=s"(wB[1]), "=s"(wB[2]), "=s"(wB[3]),
              "=s"(wB[4]), "=s"(wB[5]), "=s"(wB[6]), "=s"(wB[7]),
              "=s"(wC[0]), "=s"(wC[1]), "=s"(wC[2]), "=s"(wC[3]),
              "=s"(wC[4]), "=s"(wC[5]), "=s"(wC[6]), "=s"(wC[7])
            : "s"(sa));

        // per-acc order (tap ascending within e, ci outer) == R1 gate order
        #pragma unroll
        for (int e = 0; e < 8; e++) {
            acc[e] += xv[0] * wA[e][0];
            acc[e] += xv[1] * wA[e][1];
            acc[e] += xv[2] * wA[e][2];
            acc[e] += xv[3] * wA[e][3];
            acc[e] += xv[4] * wB[e][0];
            acc[e] += xv[5] * wB[e][1];
            acc[e] += xv[6] * wB[e][2];
            acc[e] += xv[7] * wB[e][3];
            acc[e] += xv[8] * wC[e];
        }
    }

    #pragma unroll
    for (int e = 0; e < 8; e++) red[g][p][e] = acc[e];
    __syncthreads();

    if (t < 64) {
        float s[8], bs[8];
        #pragma unroll
        for (int e = 0; e < 8; e++) {
            float v = red[0][t][e] + red[1][t][e] + red[2][t][e] + red[3][t][e];
            s[e]  = 1.0f / (1.0f + expf(-v));
            bs[e] = s[e] + gb[e];
        }
        // top-1 (ties -> lowest index, matches lax.top_k)
        int i1 = 0; float b1 = bs[0]; float w1 = s[0];
        #pragma unroll
        for (int e = 1; e < 8; e++)
            if (bs[e] > b1) { b1 = bs[e]; i1 = e; w1 = s[e]; }
        int i2 = -1; float b2 = -1e30f; float w2 = 0.f;
        #pragma unroll
        for (int e = 0; e < 8; e++)
            if (e != i1 && bs[e] > b2) { b2 = bs[e]; i2 = e; w2 = s[e]; }

        float mx = fmaxf(w1, w2);
        float e1 = expf(w1 - mx), e2 = expf(w2 - mx);
        float inv = 1.0f / (e1 + e2);
        float p1 = e1 * inv, p2 = e2 * inv;   // ROUTE_SCALE = 1

        const int hh = h2 * 2 + (t >> 5);
        const int ww = wt * 32 + (t & 31);
        int base = b * 8 * 9216 + hh * 96 + ww;
        #pragma unroll
        for (int e = 0; e < 8; e++) {
            float v = (e == i1) ? p1 : ((e == i2) ? p2 : 0.0f);
            scores[base + e * 9216] = v;
        }
    }
}

// ---------------------------------------------------------------------------
// Main: fused dense MoE conv via implicit-GEMM MFMA — byte-identical to the
// measured round-1/round-10 kernel (122 us, MfmaUtil 35%, VGPR 76).
// ---------------------------------------------------------------------------
__global__ __launch_bounds__(256, 3) void moe_main_kernel(
    const float* __restrict__ x, const unsigned short* __restrict__ pw,
    const float* __restrict__ scores, const float* __restrict__ eb,
    const float* __restrict__ sb, float* __restrict__ out)
{
    __shared__ unsigned short xs[4 * 34 * 136]; // [row(4)][col(34)][ci 128 pad->136]
    __shared__ float sc[8][64];
    __shared__ float bia[9][128];

    const int t  = threadIdx.x;
    const int bx = blockIdx.x;
    const int wt = bx % 3;
    const int h2 = (bx / 3) % 48;
    const int b  = bx / 144;
    const int h0 = h2 * 2, w0 = wt * 32;

    // ---- stage x patch (4 rows x 34 cols x 128 ci), fp32 -> bf16, transposed
    const float* xb = x + b * 128 * 9216;
    for (int i = t; i < 17408; i += 256) {
        int ci  = i / 136;
        int rem = i - ci * 136;
        int row = rem / 34;
        int col = rem - row * 34;
        int hh = h0 - 1 + row;
        int ww = w0 - 1 + col;
        float v = 0.0f;
        if (hh >= 0 && hh < 96 && ww >= 0 && ww < 96)
            v = xb[ci * 9216 + hh * 96 + ww];
        xs[(row * 34 + col) * 136 + ci] = f2bf(v);
    }
    // ---- stage routing scores for the 64 pixels
    for (int i = t; i < 512; i += 256) {
        int e = i >> 6, p = i & 63;
        sc[e][p] = scores[(b * 8 + e) * 9216 + (h0 + (p >> 5)) * 96 + (w0 + (p & 31))];
    }
    // ---- stage biases (experts + shared as e=8)
    for (int i = t; i < 1152; i += 256) {
        int e = i >> 7, co = i & 127;
        bia[e][co] = (e < 8) ? eb[(e << 7) + co] : sb[co];
    }
    __syncthreads();

    const int wv = t >> 6;
    const int l  = t & 63;
    const int lm = l & 15;   // m (A: co) / n (B: pixel) within frag
    const int lq = l >> 4;   // k-subgroup for A/B; row-group for D

    f32x4 acc[2][4], accE[2][4];
    #pragma unroll
    for (int i2 = 0; i2 < 2; i2++)
        #pragma unroll
        for (int j = 0; j < 4; j++) {
            acc[i2][j]  = (f32x4){0.f, 0.f, 0.f, 0.f};
            accE[i2][j] = (f32x4){0.f, 0.f, 0.f, 0.f};
        }

    const int bBase = lm * 136 + lq * 8;
    const uint4* pw4 = reinterpret_cast<const uint4*>(pw) + wv * 512 + l;

    uint4 afA[8], afB[8];   // A-frag double buffer: [kc*2+h]

#define LOADF(dst, etv) {                                                     \
    const uint4* _p = pw4 + (etv) * 2048;                                     \
    _Pragma("unroll")                                                         \
    for (int q = 0; q < 8; ++q) dst[q] = _p[(q >> 1) * 128 + (q & 1) * 64];   \
}

#define COMPUTE(src, etv) {                                                   \
    const int e_   = (etv) / 9;                                               \
    const int tap_ = (etv) - e_ * 9;                                          \
    const int kh_  = tap_ / 3;                                                \
    const int kw_  = tap_ - kh_ * 3;                                          \
    const int xr0  = kh_ * 4624 + kw_ * 136 + bBase;                          \
    _Pragma("unroll")                                                         \
    for (int kc = 0; kc < 4; ++kc) {                                          \
        const short8 a0 = *reinterpret_cast<const short8*>(&src[kc * 2 + 0]); \
        const short8 a1 = *reinterpret_cast<const short8*>(&src[kc * 2 + 1]); \
        _Pragma("unroll")                                                     \
        for (int j = 0; j < 4; ++j) {                                         \
            const short8 bv = *reinterpret_cast<const short8*>(               \
                &xs[xr0 + (j >> 1) * 4624 + (j & 1) * 2176 + kc * 32]);       \
            accE[0][j] = __builtin_amdgcn_mfma_f32_16x16x32_bf16(             \
                a0, bv, accE[0][j], 0, 0, 0);                                 \
            accE[1][j] = __builtin_amdgcn_mfma_f32_16x16x32_bf16(             \
                a1, bv, accE[1][j], 0, 0, 0);                                 \
        }                                                                     \
    }                                                                         \
    if (tap_ == 8) {  /* end of expert: weighted accumulate */                \
        _Pragma("unroll")                                                     \
        for (int j = 0; j < 4; ++j) {                                         \
            const int p = j * 16 + lm;                                        \
            const float s_ = (e_ < 8) ? sc[e_][p] : 1.0f;                     \
            _Pragma("unroll")                                                 \
            for (int i2 = 0; i2 < 2; ++i2)                                    \
                _Pragma("unroll")                                             \
                for (int rr = 0; rr < 4; ++rr) {                              \
                    const int co_ = wv * 32 + i2 * 16 + lq * 4 + rr;          \
                    acc[i2][j][rr] += s_ * (accE[i2][j][rr] + bia[e_][co_]);  \
                    accE[i2][j][rr] = 0.f;                                    \
                }                                                             \
        }                                                                     \
    }                                                                         \
}

    // barrier-free main loop: 81 (expert,tap) steps, A-frags double-buffered
    LOADF(afA, 0);
    for (int eu = 0; eu < 40; ++eu) {
        const int et0 = eu * 2;
        LOADF(afB, et0 + 1);
        COMPUTE(afA, et0);
        LOADF(afA, et0 + 2);     // et0+2 <= 80
        COMPUTE(afB, et0 + 1);
    }
    COMPUTE(afA, 80);
#undef COMPUTE
#undef LOADF

    // ---- store (D frag: col = lm -> pixel, row = lq*4+rr -> co)
    float* ob = out + b * 128 * 9216;
    #pragma unroll
    for (int i2 = 0; i2 < 2; i2++)
        #pragma unroll
        for (int rr = 0; rr < 4; rr++) {
            const int co = wv * 32 + i2 * 16 + lq * 4 + rr;
            #pragma unroll
            for (int j = 0; j < 4; j++) {
                const int hh = h0 + (j >> 1);
                const int ww = w0 + (j & 1) * 16 + lm;
                ob[co * 9216 + hh * 96 + ww] = acc[i2][j][rr];
            }
        }
}

// ---------------------------------------------------------------------------
extern "C" void kernel_launch(void* const* d_in, const int* in_sizes, int n_in,
                              void* d_out, int out_size, void* d_ws, size_t ws_size,
                              hipStream_t stream) {
    const float* x  = (const float*)d_in[0];
    const float* gw = (const float*)d_in[1];
    const float* gb = (const float*)d_in[2];
    const float* ew = (const float*)d_in[3];
    const float* eb = (const float*)d_in[4];
    const float* sw = (const float*)d_in[5];
    const float* sb = (const float*)d_in[6];
    float* out = (float*)d_out;

    unsigned short* pw = (unsigned short*)d_ws;                  // 2,654,208 B
    float* scores = (float*)((char*)d_ws + 2654208);             // 1,179,648 B

    gate_prep_kernel<<<720, 256, 0, stream>>>(x, gw, gb, ew, sw, scores, pw);
    moe_main_kernel<<<576, 256, 0, stream>>>(x, pw, scores, eb, sb, out);
}

// Round 12
// 205.885 us; speedup vs baseline: 1.0615x; 1.0615x over previous
//
#include <hip/hip_runtime.h>
#include <hip/hip_bf16.h>
#include <math.h>

// Problem constants
// x:(4,128,96,96) gate_w:(8,128,3,3) gate_bias:(8) expert_w:(8,128,128,3,3)
// expert_b:(8,128) shared_w:(128,128,3,3) shared_b:(128)  -> out:(4,128,96,96)

typedef __attribute__((ext_vector_type(8))) short short8;
typedef __attribute__((ext_vector_type(4))) float f32x4;

static __device__ __forceinline__ unsigned short f2bf(float f) {
    unsigned int u = __float_as_uint(f);
    unsigned int r = (u + 0x7FFFu + ((u >> 16) & 1u)) >> 16;
    return (unsigned short)r;
}

// ---------------------------------------------------------------------------
// Merged gate + prep kernel — byte-identical to round-10's (measured best:
// total rest-of-pipeline ~= 92 us; 4 weight-path variants proved the gate is
// not weight-path-bound, so keep the simplest passing version).
// ---------------------------------------------------------------------------
__global__ __launch_bounds__(256) void gate_prep_kernel(
    const float* __restrict__ x, const float* __restrict__ gw,
    const float* __restrict__ gb,
    const float* __restrict__ ew, const float* __restrict__ sw,
    float* __restrict__ scores, unsigned short* __restrict__ pw)
{
    __shared__ float red[4][64][8];            // gate partial sums (8 KB)
    __shared__ unsigned short lt2[9216];       // prep bounce (18 KB)

    const int t  = threadIdx.x;
    const int bx = blockIdx.x;

    if (bx >= 576) {
        // =================== prep transpose (144 blocks) ====================
        // pw chunk index: (e*9+tap)*2048 + wv*512 + kc*128 + h*64 + lane
        //   lane = lq*16+lm ; co = wv*32+h*16+lm ; k = kc*32+lq*8+d
        const int pblk = bx - 576;
        const int e  = pblk >> 4;
        const int wv = (pblk >> 2) & 3;
        const int kc = pblk & 3;
        const float* src = (e < 8) ? (ew + e * 147456) : sw;
        const float* sb2 = src + (wv * 32) * 1152 + kc * 288;

        #pragma unroll
        for (int j = 0; j < 36; ++j) {
            int i = t + j * 256;                 // 0..9215
            int co_l = i / 288;
            int r    = i - co_l * 288;           // k_l*9 + tap
            int k_l  = r / 9;
            int tap  = r - k_l * 9;
            float v = sb2[co_l * 1152 + r];
            lt2[tap * 1024 + (co_l >> 4) * 512 +
                ((k_l >> 3) * 16 + (co_l & 15)) * 8 + (k_l & 7)] = f2bf(v);
        }
        __syncthreads();

        uint4* pw16 = reinterpret_cast<uint4*>(pw);
        for (int c = t; c < 1152; c += 256) {
            int tap = c >> 7;
            int rem = c & 127;                   // h*64 + lane
            uint4 val = *reinterpret_cast<const uint4*>(&lt2[tap * 1024 + rem * 8]);
            pw16[(e * 9 + tap) * 2048 + wv * 512 + kc * 128 + rem] = val;
        }
        return;
    }

    // ======================= gate (576 blocks) ==============================
    const int g  = t >> 6;               // ci group (wave id)
    const int p  = t & 63;
    const int wt = bx % 3;
    const int h2 = (bx / 3) % 48;
    const int b  = bx / 144;
    const int h  = h2 * 2 + (p >> 5);
    const int w  = wt * 32 + (p & 31);

    int off[9]; float msk[9];
    #pragma unroll
    for (int kh = 0; kh < 3; kh++) {
        #pragma unroll
        for (int kw = 0; kw < 3; kw++) {
            int hh = h + kh - 1, ww = w + kw - 1;
            bool valid = (hh >= 0 && hh < 96 && ww >= 0 && ww < 96);
            int hc = min(max(hh, 0), 95), wc = min(max(ww, 0), 95);
            off[kh * 3 + kw] = hc * 96 + wc;
            msk[kh * 3 + kw] = valid ? 1.0f : 0.0f;
        }
    }

    // wave-uniform base (readfirstlane makes uniformity provable)
    const int gu = __builtin_amdgcn_readfirstlane(g);
    const float* xb = x + (b * 128 + gu * 32) * 9216;

    float acc[8] = {0.f,0.f,0.f,0.f,0.f,0.f,0.f,0.f};
    for (int ci = 0; ci < 32; ci++) {
        const float* xc = xb + ci * 9216;
        float xv[9];
        #pragma unroll
        for (int tap = 0; tap < 9; tap++) xv[tap] = xc[off[tap]] * msk[tap];

        // wave-uniform weight reads: cp uniform, e/tap compile-time
        //   w[ci][e*9+tap] = gw[(e*128 + gu*32+ci)*9 + tap]
        const float* cp = gw + (gu * 32 + ci) * 9;
        float wsc[72];
        #pragma unroll
        for (int e = 0; e < 8; e++)
            #pragma unroll
            for (int tap = 0; tap < 9; tap++)
                wsc[e * 9 + tap] = cp[e * 1152 + tap];

        // per-acc order (tap ascending within e, ci outer) == R1 gate order
        #pragma unroll
        for (int e = 0; e < 8; e++) {
            #pragma unroll
            for (int tap = 0; tap < 9; tap++)
                acc[e] += xv[tap] * wsc[e * 9 + tap];
        }
    }

    #pragma unroll
    for (int e = 0; e < 8; e++) red[g][p][e] = acc[e];
    __syncthreads();

    if (t < 64) {
        float s[8], bs[8];
        #pragma unroll
        for (int e = 0; e < 8; e++) {
            float v = red[0][t][e] + red[1][t][e] + red[2][t][e] + red[3][t][e];
            s[e]  = 1.0f / (1.0f + expf(-v));
            bs[e] = s[e] + gb[e];
        }
        // top-1 (ties -> lowest index, matches lax.top_k)
        int i1 = 0; float b1 = bs[0]; float w1 = s[0];
        #pragma unroll
        for (int e = 1; e < 8; e++)
            if (bs[e] > b1) { b1 = bs[e]; i1 = e; w1 = s[e]; }
        int i2 = -1; float b2 = -1e30f; float w2 = 0.f;
        #pragma unroll
        for (int e = 0; e < 8; e++)
            if (e != i1 && bs[e] > b2) { b2 = bs[e]; i2 = e; w2 = s[e]; }

        float mx = fmaxf(w1, w2);
        float e1 = expf(w1 - mx), e2 = expf(w2 - mx);
        float inv = 1.0f / (e1 + e2);
        float p1 = e1 * inv, p2 = e2 * inv;   // ROUTE_SCALE = 1

        const int hh = h2 * 2 + (t >> 5);
        const int ww = wt * 32 + (t & 31);
        int base = b * 8 * 9216 + hh * 96 + ww;
        #pragma unroll
        for (int e = 0; e < 8; e++) {
            float v = (e == i1) ? p1 : ((e == i2) ? p2 : 0.0f);
            scores[base + e * 9216] = v;
        }
    }
}

// ---------------------------------------------------------------------------
// Main v4: implicit-GEMM MFMA with 768-block tiling (2 rows x 24 cols = 48 px
// per block) -> exactly 3 blocks/CU, zero dispatch imbalance (576 blocks was
// 2.25/CU: 64 CUs ran 3 blocks while 192 ran 2 -> ~25% tail loss).
// Per wave: 32 co x 48 px x 128 ci; 3 B-frags/step via per-lane bofs table.
// A-path, pw layout, per-output FP order unchanged from the R1 kernel.
// ---------------------------------------------------------------------------
__global__ __launch_bounds__(256, 3) void moe_main_kernel(
    const float* __restrict__ x, const unsigned short* __restrict__ pw,
    const float* __restrict__ scores, const float* __restrict__ eb,
    const float* __restrict__ sb, float* __restrict__ out)
{
    __shared__ unsigned short xs[104 * 136];    // [hrow(4)*26+hcol][ci pad->136]
    __shared__ float sc[8][48];
    __shared__ float bia[9][128];

    const int t  = threadIdx.x;
    const int bx = blockIdx.x;
    const int wt = bx & 3;                 // 4 col-tiles of 24
    const int h2 = (bx >> 2) % 48;
    const int b  = bx / 192;
    const int h0 = h2 * 2, w0 = wt * 24;

    // ---- stage x patch (4 rows x 26 cols x 128 ci), fp32 -> bf16, transposed
    const float* xb = x + b * 128 * 9216;
    for (int i = t; i < 13312; i += 256) {
        int ci  = i / 104;
        int pix = i - ci * 104;            // hrow*26 + hcol
        int hrow = pix / 26;
        int hcol = pix - hrow * 26;
        int hh = h0 - 1 + hrow;
        int ww = w0 - 1 + hcol;
        float v = 0.0f;
        if (hh >= 0 && hh < 96 && ww >= 0 && ww < 96)
            v = xb[ci * 9216 + hh * 96 + ww];
        xs[pix * 136 + ci] = f2bf(v);
    }
    // ---- stage routing scores for the 48 pixels
    for (int i = t; i < 384; i += 256) {
        int e = i / 48, p = i - e * 48;
        sc[e][p] = scores[(b * 8 + e) * 9216 + (h0 + p / 24) * 96 + (w0 + p % 24)];
    }
    // ---- stage biases (experts + shared as e=8)
    for (int i = t; i < 1152; i += 256) {
        int e = i >> 7, co = i & 127;
        bia[e][co] = (e < 8) ? eb[(e << 7) + co] : sb[co];
    }
    __syncthreads();

    const int wv = t >> 6;
    const int l  = t & 63;
    const int lm = l & 15;   // m (A: co) / n (B: pixel) within frag
    const int lq = l >> 4;   // k-subgroup for A/B; row-group for D

    // per-lane B base offsets for the 3 pixel-frags (pixel = j*16+lm)
    int bofs[3];
    #pragma unroll
    for (int j = 0; j < 3; ++j) {
        const int px = j * 16 + lm;
        const int r = px / 24, c = px - r * 24;
        bofs[j] = ((r + 1) * 26 + (c + 1)) * 136 + lq * 8;
    }

    f32x4 acc[2][3], accE[2][3];
    #pragma unroll
    for (int i2 = 0; i2 < 2; i2++)
        #pragma unroll
        for (int j = 0; j < 3; j++) {
            acc[i2][j]  = (f32x4){0.f, 0.f, 0.f, 0.f};
            accE[i2][j] = (f32x4){0.f, 0.f, 0.f, 0.f};
        }

    const uint4* pw4 = reinterpret_cast<const uint4*>(pw) + wv * 512 + l;

    uint4 afA[8], afB[8];   // A-frag double buffer: [kc*2+h]

#define LOADF(dst, etv) {                                                     \
    const uint4* _p = pw4 + (etv) * 2048;                                     \
    _Pragma("unroll")                                                         \
    for (int q = 0; q < 8; ++q) dst[q] = _p[(q >> 1) * 128 + (q & 1) * 64];   \
}

#define COMPUTE(src, etv) {                                                   \
    const int e_   = (etv) / 9;                                               \
    const int tap_ = (etv) - e_ * 9;                                          \
    const int kh_  = tap_ / 3;                                                \
    const int kw_  = tap_ - kh_ * 3;                                          \
    const int tofs = (kh_ * 26 + kw_ - 27) * 136;                             \
    _Pragma("unroll")                                                         \
    for (int kc = 0; kc < 4; ++kc) {                                          \
        const short8 a0 = *reinterpret_cast<const short8*>(&src[kc * 2 + 0]); \
        const short8 a1 = *reinterpret_cast<const short8*>(&src[kc * 2 + 1]); \
        _Pragma("unroll")                                                     \
        for (int j = 0; j < 3; ++j) {                                         \
            const short8 bv = *reinterpret_cast<const short8*>(               \
                &xs[bofs[j] + tofs + kc * 32]);                               \
            accE[0][j] = __builtin_amdgcn_mfma_f32_16x16x32_bf16(             \
                a0, bv, accE[0][j], 0, 0, 0);                                 \
            accE[1][j] = __builtin_amdgcn_mfma_f32_16x16x32_bf16(             \
                a1, bv, accE[1][j], 0, 0, 0);                                 \
        }                                                                     \
    }                                                                         \
    if (tap_ == 8) {  /* end of expert: weighted accumulate */                \
        _Pragma("unroll")                                                     \
        for (int j = 0; j < 3; ++j) {                                         \
            const float s_ = (e_ < 8) ? sc[e_][j * 16 + lm] : 1.0f;           \
            _Pragma("unroll")                                                 \
            for (int i2 = 0; i2 < 2; ++i2)                                    \
                _Pragma("unroll")                                             \
                for (int rr = 0; rr < 4; ++rr) {                              \
                    const int co_ = wv * 32 + i2 * 16 + lq * 4 + rr;          \
                    acc[i2][j][rr] += s_ * (accE[i2][j][rr] + bia[e_][co_]);  \
                    accE[i2][j][rr] = 0.f;                                    \
                }                                                             \
        }                                                                     \
    }                                                                         \
}

    // barrier-free main loop: 81 (expert,tap) steps, A-frags double-buffered
    LOADF(afA, 0);
    for (int eu = 0; eu < 40; ++eu) {
        const int et0 = eu * 2;
        LOADF(afB, et0 + 1);
        COMPUTE(afA, et0);
        LOADF(afA, et0 + 2);     // et0+2 <= 80
        COMPUTE(afB, et0 + 1);
    }
    COMPUTE(afA, 80);
#undef COMPUTE
#undef LOADF

    // ---- store (D frag: col = lm -> pixel, row = lq*4+rr -> co)
    float* ob = out + b * 128 * 9216;
    #pragma unroll
    for (int i2 = 0; i2 < 2; i2++)
        #pragma unroll
        for (int rr = 0; rr < 4; rr++) {
            const int co = wv * 32 + i2 * 16 + lq * 4 + rr;
            #pragma unroll
            for (int j = 0; j < 3; j++) {
                const int px = j * 16 + lm;
                const int hh = h0 + px / 24;
                const int ww = w0 + (px - (px / 24) * 24);
                ob[co * 9216 + hh * 96 + ww] = acc[i2][j][rr];
            }
        }
}

// ---------------------------------------------------------------------------
extern "C" void kernel_launch(void* const* d_in, const int* in_sizes, int n_in,
                              void* d_out, int out_size, void* d_ws, size_t ws_size,
                              hipStream_t stream) {
    const float* x  = (const float*)d_in[0];
    const float* gw = (const float*)d_in[1];
    const float* gb = (const float*)d_in[2];
    const float* ew = (const float*)d_in[3];
    const float* eb = (const float*)d_in[4];
    const float* sw = (const float*)d_in[5];
    const float* sb = (const float*)d_in[6];
    float* out = (float*)d_out;

    unsigned short* pw = (unsigned short*)d_ws;                  // 2,654,208 B
    float* scores = (float*)((char*)d_ws + 2654208);             // 1,179,648 B

    gate_prep_kernel<<<720, 256, 0, stream>>>(x, gw, gb, ew, sw, scores, pw);
    moe_main_kernel<<<768, 256, 0, stream>>>(x, pw, scores, eb, sb, out);
}

// Round 13
// 191.978 us; speedup vs baseline: 1.1384x; 1.0724x over previous
//
#include <hip/hip_runtime.h>
#include <hip/hip_bf16.h>
#include <math.h>

// Problem constants
// x:(4,128,96,96) gate_w:(8,128,3,3) gate_bias:(8) expert_w:(8,128,128,3,3)
// expert_b:(8,128) shared_w:(128,128,3,3) shared_b:(128)  -> out:(4,128,96,96)

typedef __attribute__((ext_vector_type(8))) short short8;
typedef __attribute__((ext_vector_type(4))) float f32x4;

static __device__ __forceinline__ unsigned short f2bf(float f) {
    unsigned int u = __float_as_uint(f);
    unsigned int r = (u + 0x7FFFu + ((u >> 16) & 1u)) >> 16;
    return (unsigned short)r;
}

// ---------------------------------------------------------------------------
// Merged gate + prep kernel. Gate math byte-identical to round-10/12 (frozen
// FP order). NEW: XCD-aware bijective swizzle of the 576 gate tiles
// ((bx&7)*72 + bx>>3) so tiles sharing x halo rows land on the same per-XCD
// L2 (T1; 576%8==0 -> simple form is bijective).
// ---------------------------------------------------------------------------
__global__ __launch_bounds__(256) void gate_prep_kernel(
    const float* __restrict__ x, const float* __restrict__ gw,
    const float* __restrict__ gb,
    const float* __restrict__ ew, const float* __restrict__ sw,
    float* __restrict__ scores, unsigned short* __restrict__ pw)
{
    __shared__ float red[4][64][8];            // gate partial sums (8 KB)
    __shared__ unsigned short lt2[9216];       // prep bounce (18 KB)

    const int t  = threadIdx.x;
    const int bx = blockIdx.x;

    if (bx >= 576) {
        // =================== prep transpose (144 blocks) ====================
        // pw chunk index: (e*9+tap)*2048 + wv*512 + kc*128 + h*64 + lane
        //   lane = lq*16+lm ; co = wv*32+h*16+lm ; k = kc*32+lq*8+d
        const int pblk = bx - 576;
        const int e  = pblk >> 4;
        const int wv = (pblk >> 2) & 3;
        const int kc = pblk & 3;
        const float* src = (e < 8) ? (ew + e * 147456) : sw;
        const float* sb2 = src + (wv * 32) * 1152 + kc * 288;

        #pragma unroll
        for (int j = 0; j < 36; ++j) {
            int i = t + j * 256;                 // 0..9215
            int co_l = i / 288;
            int r    = i - co_l * 288;           // k_l*9 + tap
            int k_l  = r / 9;
            int tap  = r - k_l * 9;
            float v = sb2[co_l * 1152 + r];
            lt2[tap * 1024 + (co_l >> 4) * 512 +
                ((k_l >> 3) * 16 + (co_l & 15)) * 8 + (k_l & 7)] = f2bf(v);
        }
        __syncthreads();

        uint4* pw16 = reinterpret_cast<uint4*>(pw);
        for (int c = t; c < 1152; c += 256) {
            int tap = c >> 7;
            int rem = c & 127;                   // h*64 + lane
            uint4 val = *reinterpret_cast<const uint4*>(&lt2[tap * 1024 + rem * 8]);
            pw16[(e * 9 + tap) * 2048 + wv * 512 + kc * 128 + rem] = val;
        }
        return;
    }

    // ======================= gate (576 blocks) ==============================
    // XCD-aware bijective tile swizzle: 72 consecutive tiles per XCD
    const int gl = (bx & 7) * 72 + (bx >> 3);
    const int g  = t >> 6;               // ci group (wave id)
    const int p  = t & 63;
    const int wt = gl % 3;
    const int h2 = (gl / 3) % 48;
    const int b  = gl / 144;
    const int h  = h2 * 2 + (p >> 5);
    const int w  = wt * 32 + (p & 31);

    int off[9]; float msk[9];
    #pragma unroll
    for (int kh = 0; kh < 3; kh++) {
        #pragma unroll
        for (int kw = 0; kw < 3; kw++) {
            int hh = h + kh - 1, ww = w + kw - 1;
            bool valid = (hh >= 0 && hh < 96 && ww >= 0 && ww < 96);
            int hc = min(max(hh, 0), 95), wc = min(max(ww, 0), 95);
            off[kh * 3 + kw] = hc * 96 + wc;
            msk[kh * 3 + kw] = valid ? 1.0f : 0.0f;
        }
    }

    // wave-uniform base (readfirstlane makes uniformity provable)
    const int gu = __builtin_amdgcn_readfirstlane(g);
    const float* xb = x + (b * 128 + gu * 32) * 9216;

    float acc[8] = {0.f,0.f,0.f,0.f,0.f,0.f,0.f,0.f};
    for (int ci = 0; ci < 32; ci++) {
        const float* xc = xb + ci * 9216;
        float xv[9];
        #pragma unroll
        for (int tap = 0; tap < 9; tap++) xv[tap] = xc[off[tap]] * msk[tap];

        // wave-uniform weight reads: cp uniform, e/tap compile-time
        //   w[ci][e*9+tap] = gw[(e*128 + gu*32+ci)*9 + tap]
        const float* cp = gw + (gu * 32 + ci) * 9;
        float wsc[72];
        #pragma unroll
        for (int e = 0; e < 8; e++)
            #pragma unroll
            for (int tap = 0; tap < 9; tap++)
                wsc[e * 9 + tap] = cp[e * 1152 + tap];

        // per-acc order (tap ascending within e, ci outer) == R1 gate order
        #pragma unroll
        for (int e = 0; e < 8; e++) {
            #pragma unroll
            for (int tap = 0; tap < 9; tap++)
                acc[e] += xv[tap] * wsc[e * 9 + tap];
        }
    }

    #pragma unroll
    for (int e = 0; e < 8; e++) red[g][p][e] = acc[e];
    __syncthreads();

    if (t < 64) {
        float s[8], bs[8];
        #pragma unroll
        for (int e = 0; e < 8; e++) {
            float v = red[0][t][e] + red[1][t][e] + red[2][t][e] + red[3][t][e];
            s[e]  = 1.0f / (1.0f + expf(-v));
            bs[e] = s[e] + gb[e];
        }
        // top-1 (ties -> lowest index, matches lax.top_k)
        int i1 = 0; float b1 = bs[0]; float w1 = s[0];
        #pragma unroll
        for (int e = 1; e < 8; e++)
            if (bs[e] > b1) { b1 = bs[e]; i1 = e; w1 = s[e]; }
        int i2 = -1; float b2 = -1e30f; float w2 = 0.f;
        #pragma unroll
        for (int e = 0; e < 8; e++)
            if (e != i1 && bs[e] > b2) { b2 = bs[e]; i2 = e; w2 = s[e]; }

        float mx = fmaxf(w1, w2);
        float e1 = expf(w1 - mx), e2 = expf(w2 - mx);
        float inv = 1.0f / (e1 + e2);
        float p1 = e1 * inv, p2 = e2 * inv;   // ROUTE_SCALE = 1

        const int hh = h2 * 2 + (t >> 5);
        const int ww = wt * 32 + (t & 31);
        int base = b * 8 * 9216 + hh * 96 + ww;
        #pragma unroll
        for (int e = 0; e < 8; e++) {
            float v = (e == i1) ? p1 : ((e == i2) ? p2 : 0.0f);
            scores[base + e * 9216] = v;
        }
    }
}

// ---------------------------------------------------------------------------
// Main v5: R12's 768-block tiling (48 px/block, 3 blocks/CU exact) + T1
// XCD-aware bijective tile swizzle ((bx&7)*96 + bx>>3): 96 consecutive tiles
// per XCD = one contiguous ~50-row x band (2.4 MB < 4 MB per-XCD L2), so
// halo re-reads become L2 hits instead of HBM re-fetches (FETCH 48 MB for
// 23 MB unique in R12). Compute path byte-identical to R12.
// ---------------------------------------------------------------------------
__global__ __launch_bounds__(256, 3) void moe_main_kernel(
    const float* __restrict__ x, const unsigned short* __restrict__ pw,
    const float* __restrict__ scores, const float* __restrict__ eb,
    const float* __restrict__ sb, float* __restrict__ out)
{
    __shared__ unsigned short xs[104 * 136];    // [hrow(4)*26+hcol][ci pad->136]
    __shared__ float sc[8][48];
    __shared__ float bia[9][128];

    const int t  = threadIdx.x;
    const int bx = blockIdx.x;
    // XCD-aware bijective tile swizzle (768 % 8 == 0)
    const int bl = (bx & 7) * 96 + (bx >> 3);
    const int wt = bl & 3;                 // 4 col-tiles of 24
    const int h2 = (bl >> 2) % 48;
    const int b  = bl / 192;
    const int h0 = h2 * 2, w0 = wt * 24;

    // ---- stage x patch (4 rows x 26 cols x 128 ci), fp32 -> bf16, transposed
    const float* xb = x + b * 128 * 9216;
    for (int i = t; i < 13312; i += 256) {
        int ci  = i / 104;
        int pix = i - ci * 104;            // hrow*26 + hcol
        int hrow = pix / 26;
        int hcol = pix - hrow * 26;
        int hh = h0 - 1 + hrow;
        int ww = w0 - 1 + hcol;
        float v = 0.0f;
        if (hh >= 0 && hh < 96 && ww >= 0 && ww < 96)
            v = xb[ci * 9216 + hh * 96 + ww];
        xs[pix * 136 + ci] = f2bf(v);
    }
    // ---- stage routing scores for the 48 pixels
    for (int i = t; i < 384; i += 256) {
        int e = i / 48, p = i - e * 48;
        sc[e][p] = scores[(b * 8 + e) * 9216 + (h0 + p / 24) * 96 + (w0 + p % 24)];
    }
    // ---- stage biases (experts + shared as e=8)
    for (int i = t; i < 1152; i += 256) {
        int e = i >> 7, co = i & 127;
        bia[e][co] = (e < 8) ? eb[(e << 7) + co] : sb[co];
    }
    __syncthreads();

    const int wv = t >> 6;
    const int l  = t & 63;
    const int lm = l & 15;   // m (A: co) / n (B: pixel) within frag
    const int lq = l >> 4;   // k-subgroup for A/B; row-group for D

    // per-lane B base offsets for the 3 pixel-frags (pixel = j*16+lm)
    int bofs[3];
    #pragma unroll
    for (int j = 0; j < 3; ++j) {
        const int px = j * 16 + lm;
        const int r = px / 24, c = px - r * 24;
        bofs[j] = ((r + 1) * 26 + (c + 1)) * 136 + lq * 8;
    }

    f32x4 acc[2][3], accE[2][3];
    #pragma unroll
    for (int i2 = 0; i2 < 2; i2++)
        #pragma unroll
        for (int j = 0; j < 3; j++) {
            acc[i2][j]  = (f32x4){0.f, 0.f, 0.f, 0.f};
            accE[i2][j] = (f32x4){0.f, 0.f, 0.f, 0.f};
        }

    const uint4* pw4 = reinterpret_cast<const uint4*>(pw) + wv * 512 + l;

    uint4 afA[8], afB[8];   // A-frag double buffer: [kc*2+h]

#define LOADF(dst, etv) {                                                     \
    const uint4* _p = pw4 + (etv) * 2048;                                     \
    _Pragma("unroll")                                                         \
    for (int q = 0; q < 8; ++q) dst[q] = _p[(q >> 1) * 128 + (q & 1) * 64];   \
}

#define COMPUTE(src, etv) {                                                   \
    const int e_   = (etv) / 9;                                               \
    const int tap_ = (etv) - e_ * 9;                                          \
    const int kh_  = tap_ / 3;                                                \
    const int kw_  = tap_ - kh_ * 3;                                          \
    const int tofs = (kh_ * 26 + kw_ - 27) * 136;                             \
    _Pragma("unroll")                                                         \
    for (int kc = 0; kc < 4; ++kc) {                                          \
        const short8 a0 = *reinterpret_cast<const short8*>(&src[kc * 2 + 0]); \
        const short8 a1 = *reinterpret_cast<const short8*>(&src[kc * 2 + 1]); \
        _Pragma("unroll")                                                     \
        for (int j = 0; j < 3; ++j) {                                         \
            const short8 bv = *reinterpret_cast<const short8*>(               \
                &xs[bofs[j] + tofs + kc * 32]);                               \
            accE[0][j] = __builtin_amdgcn_mfma_f32_16x16x32_bf16(             \
                a0, bv, accE[0][j], 0, 0, 0);                                 \
            accE[1][j] = __builtin_amdgcn_mfma_f32_16x16x32_bf16(             \
                a1, bv, accE[1][j], 0, 0, 0);                                 \
        }                                                                     \
    }                                                                         \
    if (tap_ == 8) {  /* end of expert: weighted accumulate */                \
        _Pragma("unroll")                                                     \
        for (int j = 0; j < 3; ++j) {                                         \
            const float s_ = (e_ < 8) ? sc[e_][j * 16 + lm] : 1.0f;           \
            _Pragma("unroll")                                                 \
            for (int i2 = 0; i2 < 2; ++i2)                                    \
                _Pragma("unroll")                                             \
                for (int rr = 0; rr < 4; ++rr) {                              \
                    const int co_ = wv * 32 + i2 * 16 + lq * 4 + rr;          \
                    acc[i2][j][rr] += s_ * (accE[i2][j][rr] + bia[e_][co_]);  \
                    accE[i2][j][rr] = 0.f;                                    \
                }                                                             \
        }                                                                     \
    }                                                                         \
}

    // barrier-free main loop: 81 (expert,tap) steps, A-frags double-buffered
    LOADF(afA, 0);
    for (int eu = 0; eu < 40; ++eu) {
        const int et0 = eu * 2;
        LOADF(afB, et0 + 1);
        COMPUTE(afA, et0);
        LOADF(afA, et0 + 2);     // et0+2 <= 80
        COMPUTE(afB, et0 + 1);
    }
    COMPUTE(afA, 80);
#undef COMPUTE
#undef LOADF

    // ---- store (D frag: col = lm -> pixel, row = lq*4+rr -> co)
    float* ob = out + b * 128 * 9216;
    #pragma unroll
    for (int i2 = 0; i2 < 2; i2++)
        #pragma unroll
        for (int rr = 0; rr < 4; rr++) {
            const int co = wv * 32 + i2 * 16 + lq * 4 + rr;
            #pragma unroll
            for (int j = 0; j < 3; j++) {
                const int px = j * 16 + lm;
                const int hh = h0 + px / 24;
                const int ww = w0 + (px - (px / 24) * 24);
                ob[co * 9216 + hh * 96 + ww] = acc[i2][j][rr];
            }
        }
}

// ---------------------------------------------------------------------------
extern "C" void kernel_launch(void* const* d_in, const int* in_sizes, int n_in,
                              void* d_out, int out_size, void* d_ws, size_t ws_size,
                              hipStream_t stream) {
    const float* x  = (const float*)d_in[0];
    const float* gw = (const float*)d_in[1];
    const float* gb = (const float*)d_in[2];
    const float* ew = (const float*)d_in[3];
    const float* eb = (const float*)d_in[4];
    const float* sw = (const float*)d_in[5];
    const float* sb = (const float*)d_in[6];
    float* out = (float*)d_out;

    unsigned short* pw = (unsigned short*)d_ws;                  // 2,654,208 B
    float* scores = (float*)((char*)d_ws + 2654208);             // 1,179,648 B

    gate_prep_kernel<<<720, 256, 0, stream>>>(x, gw, gb, ew, sw, scores, pw);
    moe_main_kernel<<<768, 256, 0, stream>>>(x, pw, scores, eb, sb, out);
}